// Round 5
// baseline (764.374 us; speedup 1.0000x reference)
//
#include <hip/hip_runtime.h>
#include <hip/hip_cooperative_groups.h>

namespace cg = cooperative_groups;

// MultiHeadedAttentionBlur on MI355X.
// Key trick: blur is linear over the key axis -> blur K once (12.6 MB)
// instead of the logits (402 MB). Then fused MFMA attention + softmax.
// R0 (535.8us verified): LDS-tiled proj GEMM (global_load_lds w16 + XOR
//     swizzle), exp2-domain softmax (fold 0.125*log2e into q).
// R1-R3: nt stores, 64KB fused blur, swapped-MFMA attn all regressed/noise.
// R4 (522.8us verified): lean fused blur (20KB LDS, 1536 tiles) -13us ->
//     evidence that each kernel boundary costs ~5-9us (traffic delta was
//     only ~3us). 3 boundaries remain = the largest controllable cost.
// R5: ONE structural change: cooperative MEGA-KERNEL. All 4 phases verbatim
//     (bitwise-identical numerics -> absmax must stay 1.525879e-05),
//     separated by grid.sync() instead of kernel boundaries.
//     Capacity by construction: 768 blocks = 3/CU, __launch_bounds__(256,3)
//     caps VGPR ~168 (phases need ~130), LDS 32KB*3=96<=160KB, 12<=32 waves.
//     Runtime fallback to the verified R4 4-kernel path if coop launch fails.
//
// ws layout (ushorts):
//   xb   [8192][768]      bf16 x
//   wb   [1536][768]      bf16 W rows 768..2303 (k then q chunks)
//   qh   [96][1024][64]   bf16 q heads, pre-scaled by 0.125*log2(e)
//   kh   [96][1024][64]   bf16 k heads
//   kt   [96][1024][64]   fully blurred k

typedef __attribute__((ext_vector_type(8))) short short8;
typedef __attribute__((ext_vector_type(4))) float f32x4;

__device__ __forceinline__ float bf2f(unsigned short u) {
    unsigned int v = ((unsigned int)u) << 16;
    return __builtin_bit_cast(float, v);
}
__device__ __forceinline__ unsigned short f2bf(float f) {
    unsigned int u = __builtin_bit_cast(unsigned int, f);
    u += 0x7FFFu + ((u >> 16) & 1u);   // round-to-nearest-even
    return (unsigned short)(u >> 16);
}

__device__ __forceinline__ void g2lds16(const unsigned short* g, unsigned short* l) {
    __builtin_amdgcn_global_load_lds(
        (const __attribute__((address_space(1))) void*)g,
        (__attribute__((address_space(3))) void*)l, 16, 0, 0);
}

#if defined(__has_builtin) && __has_builtin(__builtin_amdgcn_exp2f)
#define EXP2F(x) __builtin_amdgcn_exp2f(x)
#else
#define EXP2F(x) exp2f(x)
#endif

// 0.125 (SCALE) * log2(e): softmax done in exp2 domain, saves a mul per elem.
#define QSCALE 0.1803368801111204f

// ===================== phase bodies (shared by mega + fallback) =============

__device__ __forceinline__ void cast_body(int i, const float* __restrict__ x,
                                          const float* __restrict__ w,
                                          unsigned short* __restrict__ dst) {
    const int NX = 8 * 1024 * 768;                 // 6291456
    float4 v;
    if (i < NX) v = *(const float4*)(x + i);
    else        v = *(const float4*)(w + 768 * 768 + (i - NX));
    ushort4 o;
    o.x = f2bf(v.x); o.y = f2bf(v.y); o.z = f2bf(v.z); o.w = f2bf(v.w);
    *(ushort4*)(dst + i) = o;
}

// proj: 128x128 block tile, BK=64, global_load_lds w16 staging, XOR chunk
// swizzle (applied to the GLOBAL source address since LDS dest is lane-fixed).
// 4 waves in 2x2, each computing 64x64 via 4x4 MFMA 16x16x32 tiles.
__device__ __forceinline__ void proj_body(int bx, int by, int tid,
                                          unsigned short* As, unsigned short* Bs,
                                          const unsigned short* __restrict__ xb,
                                          const unsigned short* __restrict__ wb,
                                          unsigned short* __restrict__ qh,
                                          unsigned short* __restrict__ kh) {
    const int lane = tid & 63;
    const int wv   = tid >> 6;
    const int m0   = bx * 128;   // token tile base
    const int n0   = by * 128;   // feature tile base (0..1535)
    const int col  = lane & 15;
    const int quad = lane >> 4;
    const int wm   = (wv >> 1) * 64;
    const int wn   = (wv & 1) * 64;

    const int srow   = wv * 32 + (lane >> 3);
    const int schunk = ((lane & 7) ^ ((lane >> 3) & 7)) * 8;  // shorts
    const unsigned short* ag = xb + (size_t)(m0 + srow) * 768 + schunk;
    const unsigned short* bg = wb + (size_t)(n0 + srow) * 768 + schunk;
    unsigned short* al = As + (wv * 32) * 64;   // wave-uniform LDS base
    unsigned short* bl = Bs + (wv * 32) * 64;

    f32x4 acc[4][4] = {};

    for (int kk = 0; kk < 768; kk += 64) {
        __syncthreads();   // previous iter's LDS reads done
#pragma unroll
        for (int j = 0; j < 4; ++j) {
            g2lds16(ag + j * 8 * 768 + kk, al + j * 8 * 64);
            g2lds16(bg + j * 8 * 768 + kk, bl + j * 8 * 64);
        }
        __syncthreads();   // staging visible

#pragma unroll
        for (int kc = 0; kc < 2; ++kc) {
            const int ch = ((kc * 4 + quad) ^ (col & 7)) * 8;  // swizzled 16B chunk
            short8 a[4], b[4];
#pragma unroll
            for (int mt = 0; mt < 4; ++mt)
                a[mt] = *(const short8*)(const void*)(As + (wm + mt * 16 + col) * 64 + ch);
#pragma unroll
            for (int nt = 0; nt < 4; ++nt)
                b[nt] = *(const short8*)(const void*)(Bs + (wn + nt * 16 + col) * 64 + ch);
#pragma unroll
            for (int mt = 0; mt < 4; ++mt)
#pragma unroll
                for (int nt = 0; nt < 4; ++nt)
                    acc[mt][nt] = __builtin_amdgcn_mfma_f32_16x16x32_bf16(
                        a[mt], b[nt], acc[mt][nt], 0, 0, 0);
        }
    }

    // epilogue: scatter into head-major q/k arrays; fold QSCALE into q.
#pragma unroll
    for (int nt = 0; nt < 4; ++nt) {
        int f = n0 + wn + nt * 16 + col;
        bool isq = (f >= 768);
        int fl = isq ? (f - 768) : f;
        int h = fl >> 6, d = fl & 63;
        unsigned short* dstb = isq ? qh : kh;
        float scl = isq ? QSCALE : 1.0f;
#pragma unroll
        for (int mt = 0; mt < 4; ++mt) {
#pragma unroll
            for (int i = 0; i < 4; ++i) {
                int t = m0 + wm + mt * 16 + quad * 4 + i;   // token
                int n = (t >> 10) * 12 + h;                 // head index b*12+h
                dstb[((n << 10) + (t & 1023)) * 64 + d] = f2bf(acc[mt][nt][i] * scl);
            }
        }
    }
}

// blur: one tile per (head n, 8-key-row tile rt, 16-channel slice).
// 12 halo rows x 32 x 16ch in (12 KB) + 8x32x16 bf16 tmp (8 KB) = 20 KB.
__device__ __forceinline__ void blur_body(int bxx, int n, int tid,
                                          unsigned short* sin_, unsigned short* stm_,
                                          const unsigned short* __restrict__ src,
                                          unsigned short* __restrict__ dst) {
    const int rt  = bxx & 3;          // key-row tile (8 rows each)
    const int dc  = (bxx >> 2) * 16;  // channel base (0,16,32,48)
    const int r0  = rt * 8;
    const float g5[5] = {0.054488684f, 0.24420134f, 0.40261995f, 0.24420134f, 0.054488684f};

    // load 12 halo rows x 32 cols x 16 ch, reflecting rows at load time
#pragma unroll
    for (int it = 0; it < 6; ++it) {
        int l   = it * 256 + tid;   // [0,1536) uint2 units
        int row = l >> 7;           // 0..11
        int c   = (l >> 2) & 31;
        int gq  = l & 3;
        int pr  = r0 + row - 2;
        if (pr < 0)  pr = -pr;      // reflect (no edge repeat)
        if (pr > 31) pr = 62 - pr;
        *(uint2*)(void*)(sin_ + ((row * 32 + c) << 4) + gq * 4) =
            *(const uint2*)(const void*)(src + (((size_t)n << 10) + pr * 32 + c) * 64 + dc + gq * 4);
    }
    __syncthreads();

    // vertical pass -> bf16 tmp (identical rounding to the two-pass version)
#pragma unroll
    for (int it = 0; it < 4; ++it) {
        int l   = it * 256 + tid;   // [0,1024)
        int row = l >> 7;           // 0..7
        int c   = (l >> 2) & 31;
        int gq  = l & 3;
        float a0 = 0.f, a1 = 0.f, a2 = 0.f, a3 = 0.f;
#pragma unroll
        for (int o = 0; o < 5; ++o) {
            uint2 u = *(const uint2*)(const void*)(sin_ + (((row + o) * 32 + c) << 4) + gq * 4);
            float w = g5[o];
            a0 += w * bf2f((unsigned short)(u.x & 0xffff));
            a1 += w * bf2f((unsigned short)(u.x >> 16));
            a2 += w * bf2f((unsigned short)(u.y & 0xffff));
            a3 += w * bf2f((unsigned short)(u.y >> 16));
        }
        uint2 ov;
        ov.x = (unsigned)f2bf(a0) | ((unsigned)f2bf(a1) << 16);
        ov.y = (unsigned)f2bf(a2) | ((unsigned)f2bf(a3) << 16);
        *(uint2*)(void*)(stm_ + ((row * 32 + c) << 4) + gq * 4) = ov;
    }
    __syncthreads();

    // horizontal pass (cols 0..31 fully resident in LDS) -> global
#pragma unroll
    for (int it = 0; it < 4; ++it) {
        int l   = it * 256 + tid;
        int row = l >> 7;
        int c   = (l >> 2) & 31;
        int gq  = l & 3;
        float a0 = 0.f, a1 = 0.f, a2 = 0.f, a3 = 0.f;
#pragma unroll
        for (int o = -2; o <= 2; ++o) {
            int pc = c + o;
            if (pc < 0)  pc = -pc;
            if (pc > 31) pc = 62 - pc;
            uint2 u = *(const uint2*)(const void*)(stm_ + ((row * 32 + pc) << 4) + gq * 4);
            float w = g5[o + 2];
            a0 += w * bf2f((unsigned short)(u.x & 0xffff));
            a1 += w * bf2f((unsigned short)(u.x >> 16));
            a2 += w * bf2f((unsigned short)(u.y & 0xffff));
            a3 += w * bf2f((unsigned short)(u.y >> 16));
        }
        uint2 ov;
        ov.x = (unsigned)f2bf(a0) | ((unsigned)f2bf(a1) << 16);
        ov.y = (unsigned)f2bf(a2) | ((unsigned)f2bf(a3) << 16);
        *(uint2*)(void*)(dst + (((size_t)n << 10) + (r0 + row) * 32 + c) * 64 + dc + gq * 4) = ov;
    }
}

// attn: 16 queries of one head. Wave w owns keys [w*256, w*256+256).
// R0-verbatim numerics (twice-verified config).
__device__ __forceinline__ void attn_body(int s0, int n, int tid,
                                          float* redf,   // [2][4][16] floats
                                          const unsigned short* __restrict__ qh,
                                          const unsigned short* __restrict__ kt,
                                          float* __restrict__ out) {
    const int lane = tid & 63;
    const int wv   = tid >> 6;
    const int col  = lane & 15;
    const int kq   = (lane >> 4) * 8;

#define RED(a, b, c) redf[((a) * 4 + (b)) * 16 + (c)]

    const unsigned short* qp = qh + ((n << 10) + s0 + col) * 64 + kq;
    short8 a0 = *(const short8*)(const void*)(qp);
    short8 a1 = *(const short8*)(const void*)(qp + 32);

    f32x4 acc[16];
    const unsigned short* kp = kt + ((n << 10) + wv * 256 + col) * 64 + kq;
#pragma unroll
    for (int t = 0; t < 16; ++t) {
        short8 b0 = *(const short8*)(const void*)(kp + t * 1024);
        short8 b1 = *(const short8*)(const void*)(kp + t * 1024 + 32);
        f32x4 c = {};
        c = __builtin_amdgcn_mfma_f32_16x16x32_bf16(a0, b0, c, 0, 0, 0);
        c = __builtin_amdgcn_mfma_f32_16x16x32_bf16(a1, b1, c, 0, 0, 0);
        acc[t] = c;
    }

    // per-query max over this wave's 256 keys
    float mx[4];
#pragma unroll
    for (int i = 0; i < 4; ++i) {
        float m = acc[0][i];
#pragma unroll
        for (int t = 1; t < 16; ++t) m = fmaxf(m, acc[t][i]);
#pragma unroll
        for (int off = 1; off < 16; off <<= 1) m = fmaxf(m, __shfl_xor(m, off, 64));
        mx[i] = m;
    }
    if (col == 0) {
#pragma unroll
        for (int i = 0; i < 4; ++i) RED(0, wv, (lane >> 4) * 4 + i) = mx[i];
    }
    __syncthreads();

    float sm[4];
#pragma unroll
    for (int i = 0; i < 4; ++i) {
        int qloc = (lane >> 4) * 4 + i;
        float m = fmaxf(fmaxf(RED(0, 0, qloc), RED(0, 1, qloc)),
                        fmaxf(RED(0, 2, qloc), RED(0, 3, qloc)));
        float s = 0.f;
#pragma unroll
        for (int t = 0; t < 16; ++t) {
            float e = EXP2F(acc[t][i] - m);   // logits already in log2e domain
            acc[t][i] = e;
            s += e;
        }
#pragma unroll
        for (int off = 1; off < 16; off <<= 1) s += __shfl_xor(s, off, 64);
        sm[i] = s;
    }
    if (col == 0) {
#pragma unroll
        for (int i = 0; i < 4; ++i) RED(1, wv, (lane >> 4) * 4 + i) = sm[i];
    }
    __syncthreads();

#pragma unroll
    for (int i = 0; i < 4; ++i) {
        int qloc = (lane >> 4) * 4 + i;
        float s = RED(1, 0, qloc) + RED(1, 1, qloc) + RED(1, 2, qloc) + RED(1, 3, qloc);
        float inv = 1.0f / s;
        float* op = out + (((size_t)(n << 10) + s0 + qloc) << 10) + wv * 256 + col;
#pragma unroll
        for (int t = 0; t < 16; ++t) op[t * 16] = acc[t][i] * inv;
    }
#undef RED
}

// ===================== mega-kernel (cooperative) ============================
// 768 blocks x 256 threads = 3 blocks/CU by construction:
//   LDS 32KB*3 = 96 <= 160 KB; __launch_bounds__(256,3) caps VGPR ~168;
//   12 waves/CU <= 32. Grid-stride for phases with larger virtual grids.
__global__ __launch_bounds__(256, 3) void k_mega(const float* __restrict__ x,
                                                 const float* __restrict__ W,
                                                 unsigned short* __restrict__ xb,
                                                 unsigned short* __restrict__ wb,
                                                 unsigned short* __restrict__ qh,
                                                 unsigned short* __restrict__ kh,
                                                 unsigned short* __restrict__ kt,
                                                 float* __restrict__ out) {
    __shared__ __align__(16) char smem[32768];
    const int bid = blockIdx.x;
    const int tid = threadIdx.x;
    cg::grid_group grid = cg::this_grid();

    // ---- phase 0: cast (virtual grid 7296 blocks -> grid-stride) ----
    {
        const int TOT4 = 7471104 / 4;        // 1867776 float4 units
        for (int i4 = bid * 256 + tid; i4 < TOT4; i4 += 768 * 256)
            cast_body(i4 * 4, x, W, xb);
    }
    grid.sync();

    // ---- phase 1: proj (exactly 768 tiles = 1 per block) ----
    proj_body(bid & 63, bid >> 6, tid,
              (unsigned short*)smem, (unsigned short*)(smem + 16384),
              xb, wb, qh, kh);
    grid.sync();

    // ---- phase 2: blur (virtual grid 1536 = 2 per block) ----
    for (int vb = bid; vb < 1536; vb += 768)
        blur_body(vb & 15, vb >> 4, tid,
                  (unsigned short*)smem, (unsigned short*)(smem + 12288),
                  kh, kt);
    grid.sync();

    // ---- phase 3: attn (virtual grid 6144 = 8 per block) ----
    for (int va = bid; va < 6144; va += 768)
        attn_body((va & 63) * 16, va >> 6, tid, (float*)smem, qh, kt, out);
}

// ===================== fallback standalone kernels (R4-verbatim path) =======
__global__ __launch_bounds__(256) void k_cast(const float* __restrict__ x,
                                              const float* __restrict__ w,
                                              unsigned short* __restrict__ dst) {
    int i = (blockIdx.x * 256 + threadIdx.x) * 4;
    cast_body(i, x, w, dst);
}

__global__ __launch_bounds__(256) void k_proj(const unsigned short* __restrict__ xb,
                                              const unsigned short* __restrict__ wb,
                                              unsigned short* __restrict__ qh,
                                              unsigned short* __restrict__ kh) {
    __shared__ __align__(16) unsigned short As[128 * 64];
    __shared__ __align__(16) unsigned short Bs[128 * 64];
    proj_body(blockIdx.x, blockIdx.y, threadIdx.x, As, Bs, xb, wb, qh, kh);
}

__global__ __launch_bounds__(256) void k_blurf(const unsigned short* __restrict__ src,
                                               unsigned short* __restrict__ dst) {
    __shared__ __align__(16) unsigned short sin_[12 * 32 * 16];
    __shared__ __align__(16) unsigned short stm_[8 * 32 * 16];
    blur_body(blockIdx.x, blockIdx.y, threadIdx.x, sin_, stm_, src, dst);
}

__global__ __launch_bounds__(256) void k_attn(const unsigned short* __restrict__ qh,
                                              const unsigned short* __restrict__ kt,
                                              float* __restrict__ out) {
    __shared__ __align__(16) float red[2 * 4 * 16];
    attn_body(blockIdx.x * 16, blockIdx.y, threadIdx.x, red, qh, kt, out);
}

extern "C" void kernel_launch(void* const* d_in, const int* in_sizes, int n_in,
                              void* d_out, int out_size, void* d_ws, size_t ws_size,
                              hipStream_t stream) {
    const float* x = (const float*)d_in[0];
    const float* W = (const float*)d_in[1];
    float* out = (float*)d_out;

    unsigned short* ws   = (unsigned short*)d_ws;
    unsigned short* xb   = ws;                 // 6291456
    unsigned short* wb   = xb + 6291456;       // 1179648 (contiguous with xb)
    unsigned short* qh   = wb + 1179648;       // 6291456
    unsigned short* kh   = qh + 6291456;       // 6291456
    unsigned short* kt   = kh + 6291456;       // 6291456  (total ~52.7 MB)

    void* args[] = {(void*)&x, (void*)&W, (void*)&xb, (void*)&wb,
                    (void*)&qh, (void*)&kh, (void*)&kt, (void*)&out};
    hipError_t err = hipLaunchCooperativeKernel((const void*)k_mega,
                                                dim3(768), dim3(256),
                                                args, 0, stream);
    if (err != hipSuccess) {
        // fallback: verified R4 4-kernel path
        k_cast<<<7296, 256, 0, stream>>>(x, W, xb);
        k_proj<<<dim3(64, 12), 256, 0, stream>>>(xb, wb, qh, kh);
        k_blurf<<<dim3(16, 96), 256, 0, stream>>>(kh, kt);
        k_attn<<<dim3(64, 96), 256, 0, stream>>>(qh, kt, out);
    }
}